// Round 9
// baseline (153.800 us; speedup 1.0000x reference)
//
#include <hip/hip_runtime.h>
#include <cstdint>

typedef __attribute__((ext_vector_type(8))) __bf16 bf16x8;
typedef __attribute__((ext_vector_type(4))) float f32x4;
typedef __attribute__((ext_vector_type(4))) uint32_t u32x4;

// ---- problem constants ----
#define NB   16
#define CIN  256
#define COUT 256
#define HP   66          // padded H
#define WP   66          // padded W
#define KTOT 2304        // 9*256
#define XPB  (HP*WP*256)            // elems per batch image = 1,115,136
#define XPAD_ELEMS (NB*XPB)

__device__ __forceinline__ uint16_t f2bf(float f) {
  uint32_t u = __builtin_bit_cast(uint32_t, f);
  u = (u + 0x7FFFu + ((u >> 16) & 1u)) >> 16;   // round-to-nearest-even
  return (uint16_t)u;
}

// ---------------- fused prep: xpose (2048 blk) | border (1040 blk) | wprep (288 blk)
__global__ void prep_kernel(const float* __restrict__ x, const float* __restrict__ w,
                            uint16_t* __restrict__ xpad, uint16_t* __restrict__ bw) {
  const int bid = blockIdx.x;
  const int tid = threadIdx.x;
  if (bid < 2048) {
    // transpose+cast: x NCHW fp32 -> xpad[b][h+1][w+1][c] bf16 (interior only)
    const int lane = tid & 63;
    const int wvi = tid >> 6;                 // 0..3
    const int chalf = bid & 1;
    const int h = (bid >> 1) & 63;
    const int b = bid >> 7;
    const int cg = lane >> 4;                 // 0..3
    const int w4 = (lane & 15) * 4;           // 0,4,...,60
    const int c0 = chalf * 128 + wvi * 32 + cg * 8;   // 8-channel group
    const float* src = x + ((size_t)(b * 256 + c0) * 64 + h) * 64 + w4;
    f32x4 v[8];
    #pragma unroll
    for (int j = 0; j < 8; ++j)
      v[j] = *(const f32x4*)(src + (size_t)j * 4096);
    uint16_t* dst = xpad + ((size_t)(b * HP + h + 1) * WP + 1 + w4) * 256 + c0;
    #pragma unroll
    for (int p = 0; p < 4; ++p) {             // 4 pixels per thread
      u32x4 d;
      #pragma unroll
      for (int k = 0; k < 4; ++k)
        d[k] = (uint32_t)f2bf(v[2 * k][p]) | ((uint32_t)f2bf(v[2 * k + 1][p]) << 16);
      *(u32x4*)(dst + p * 256) = d;
    }
  } else if (bid < 3088) {
    // zero the pad border (u64 stores)
    const int idx = (bid - 2048) * 256 + tid;   // 0 .. 266239 exact
    const int b = idx / 16640;
    const int r = idx - b * 16640;
    uint64_t* base = (uint64_t*)(xpad + (size_t)b * XPB);
    int off;
    if (r < 4224) {                    // h=0 full row
      off = r;
    } else if (r < 8448) {             // h=65 full row
      off = 274560 + (r - 4224);
    } else if (r < 12544) {            // w=0 column, h=1..64
      const int i = r - 8448;
      off = (1 + (i >> 6)) * 4224 + (i & 63);
    } else {                           // w=65 column, h=1..64
      const int i = r - 12544;
      off = (1 + (i >> 6)) * 4224 + 4160 + (i & 63);
    }
    base[off] = 0;
  } else {
    // weight reorder: w[co][ci][3][3] fp32 -> bw[co][tap][ci] bf16
    const int gid = (bid - 3088) * 256 + tid;   // 0 .. 73727
    const int co = gid / 288;                   // 288 = 9 taps * 32 ci-groups
    const int r = gid - co * 288;
    const int tap = r >> 5;
    const int ci0 = (r & 31) * 8;
    u32x4 d;
    #pragma unroll
    for (int k = 0; k < 4; ++k) {
      const float v0 = w[((co * 256 + ci0 + 2 * k + 0) * 9) + tap];
      const float v1 = w[((co * 256 + ci0 + 2 * k + 1) * 9) + tap];
      d[k] = (uint32_t)f2bf(v0) | ((uint32_t)f2bf(v1) << 16);
    }
    *(u32x4*)(bw + co * KTOT + tap * 256 + ci0) = d;
  }
}

// ---------------- async 16B global -> LDS --------------------------------------------
__device__ __forceinline__ void gl_lds16(const void* g, void* l) {
  __builtin_amdgcn_global_load_lds(
      (__attribute__((address_space(1))) void*)(uintptr_t)g,
      (__attribute__((address_space(3))) void*)(uint32_t)(uintptr_t)l,
      16, 0, 0);
}

// ---------------- implicit GEMM v10: BM=128, BN=64, BK=64; 256 threads (4 waves) ----
// = v9's proven counted-vmcnt pipeline (3-buffer A, depth-2, raw s_barrier,
//   2 blocks/CU) with B moved LDS -> named VGPRs (v8-proven fragments/macros).
// LDS traffic/block-iter: 72 KB -> 48 KB (A write 16 + A read 32); per-CU LDS
// time ~12.8 us, just under the L2 staging wall (~13 us). LDS = 48 KB.
// vmcnt invariant: EVERY iteration issues exactly 8 VMEM ops (4 gl_lds16 A +
// 4 dwordx4 B). At iteration it's wait, the newest 8 ops are iter (it-1)'s
// prefetches, so vmcnt(8) ==> A(it) (and older) retired, regardless of intra-
// iteration reordering. B-register readiness = compiler-tracked reg deps.
// No scratch (all-named regs; v8 measured VGPR=56 with this pattern).
__global__ __launch_bounds__(256, 2) void gemm_kernel(
    const uint16_t* __restrict__ xpad, const uint16_t* __restrict__ bw,
    const float* __restrict__ bias, float* __restrict__ out) {
  __shared__ uint16_t lA[3][128 * 64];   // 16 KB per buffer, 48 KB total
  const int tid = threadIdx.x;
  const int wv = tid >> 6, lane = tid & 63;
  const int quad = lane >> 4, l15 = lane & 15, l7 = lane & 7;
  const int wm = wv >> 1, wn = wv & 1;     // 2x2 wave grid: wave tile 64(M) x 32(N)

  // XCD swizzle: 4 n-tiles of one m-tile consecutive on one XCD (A L2-local)
  const int xcd = blockIdx.x & 7;
  const int grp = blockIdx.x >> 3;        // 0..63 per XCD
  const int mtile = xcd * 16 + (grp >> 2);   // 0..127
  const int ntile = grp & 3;                 // 0..3
  const int n0 = ntile * 64;
  const int m0 = mtile * 128;
  const int bidx = m0 >> 10;              // batch image
  const int q0 = m0 & 1023;               // permuted pixel offset (multiple of 128)

  // A staging: 4 chunk-slots/thread (1024 chunks of 16B); XOR chunk swizzle
  int a_goff[4];
  #pragma unroll
  for (int t = 0; t < 4; ++t) {
    const int slot = t * 256 + tid;
    const int row = slot >> 3;            // 0..127
    const int kc = (slot & 7) ^ (row & 7);
    const int p = q0 + row;
    const int oh = 2 * ((p >> 4) & 15) + ((p >> 9) & 1);
    const int ow = 2 * (p & 15) + ((p >> 8) & 1);
    a_goff[t] = ((bidx * HP + 2 * oh) * WP + 2 * ow) * 256 + kc * 8;
  }

  // B per-lane column pointers (wave's 32 cols = 2 x 16): frag = 16B of bw
  const uint16_t* bcol0 = bw + (size_t)(n0 + wn * 32 + 0 * 16 + l15) * KTOT + quad * 8;
  const uint16_t* bcol1 = bw + (size_t)(n0 + wn * 32 + 1 * 16 + l15) * KTOT + quad * 8;

  // A LDS frag byte-offsets (swizzle-matched)
  #define AOFF(r, s) ((wm * 64 + (r) * 16 + l15) * 128 + ((((s) * 4 + quad) ^ l7) * 16))
  const int aoff00 = AOFF(0, 0), aoff01 = AOFF(0, 1);
  const int aoff10 = AOFF(1, 0), aoff11 = AOFF(1, 1);
  const int aoff20 = AOFF(2, 0), aoff21 = AOFF(2, 1);
  const int aoff30 = AOFF(3, 0), aoff31 = AOFF(3, 1);
  #undef AOFF

  f32x4 acc00{0,0,0,0}, acc01{0,0,0,0};
  f32x4 acc10{0,0,0,0}, acc11{0,0,0,0};
  f32x4 acc20{0,0,0,0}, acc21{0,0,0,0};
  f32x4 acc30{0,0,0,0}, acc31{0,0,0,0};

  auto stageA = [&](int it, int buf) {
    const int tap = it >> 2;
    const int kh = tap / 3, kw = tap - kh * 3;
    const int ci0 = (it & 3) << 6;
    const uint16_t* aptr = xpad + (kh * WP + kw) * 256 + ci0;
    char* la_ = (char*)&lA[buf][0];
    #pragma unroll
    for (int t = 0; t < 4; ++t)
      gl_lds16(aptr + a_goff[t], la_ + (t * 256 + wv * 64) * 16);
  };

  // B frags into named regs: R0=(c0,s0) R1=(c0,s1) R2=(c1,s0) R3=(c1,s1)
  #define LOADB(it, R0, R1, R2, R3) do {                                        \
    const int _ko = ((it) >> 2) * 256 + (((it) & 3) << 6);                      \
    R0 = *(const bf16x8*)(bcol0 + _ko);  R1 = *(const bf16x8*)(bcol0 + _ko + 32); \
    R2 = *(const bf16x8*)(bcol1 + _ko);  R3 = *(const bf16x8*)(bcol1 + _ko + 32); \
  } while (0)

  #define MFMA __builtin_amdgcn_mfma_f32_16x16x32_bf16
  #define COMPUTE(buf, R0, R1, R2, R3) do {                                     \
    const char* _la = (const char*)&lA[buf][0];                                 \
    bf16x8 _a0 = *(const bf16x8*)(_la + aoff00);                                \
    bf16x8 _a1 = *(const bf16x8*)(_la + aoff10);                                \
    bf16x8 _a2 = *(const bf16x8*)(_la + aoff20);                                \
    bf16x8 _a3 = *(const bf16x8*)(_la + aoff30);                                \
    acc00 = MFMA(_a0, R0, acc00, 0,0,0);  acc01 = MFMA(_a0, R2, acc01, 0,0,0);  \
    acc10 = MFMA(_a1, R0, acc10, 0,0,0);  acc11 = MFMA(_a1, R2, acc11, 0,0,0);  \
    acc20 = MFMA(_a2, R0, acc20, 0,0,0);  acc21 = MFMA(_a2, R2, acc21, 0,0,0);  \
    acc30 = MFMA(_a3, R0, acc30, 0,0,0);  acc31 = MFMA(_a3, R2, acc31, 0,0,0);  \
    _a0 = *(const bf16x8*)(_la + aoff01);                                       \
    _a1 = *(const bf16x8*)(_la + aoff11);                                       \
    _a2 = *(const bf16x8*)(_la + aoff21);                                       \
    _a3 = *(const bf16x8*)(_la + aoff31);                                       \
    acc00 = MFMA(_a0, R1, acc00, 0,0,0);  acc01 = MFMA(_a0, R3, acc01, 0,0,0);  \
    acc10 = MFMA(_a1, R1, acc10, 0,0,0);  acc11 = MFMA(_a1, R3, acc11, 0,0,0);  \
    acc20 = MFMA(_a2, R1, acc20, 0,0,0);  acc21 = MFMA(_a2, R3, acc21, 0,0,0);  \
    acc30 = MFMA(_a3, R1, acc30, 0,0,0);  acc31 = MFMA(_a3, R3, acc31, 0,0,0);  \
  } while (0)

  bf16x8 pa0, pa1, pa2, pa3;   // B double-buffer, named regs: B(even)->pa, B(odd)->pb
  bf16x8 pb0, pb1, pb2, pb3;

  // prologue: A(0)->buf0, A(1)->buf1, B(0)->pa   [12 VMEM ops outstanding]
  stageA(0, 0);
  stageA(1, 1);
  LOADB(0, pa0, pa1, pa2, pa3);

  // invariant at iter it's wait: newest 8 VMEM ops = iter(it-1)'s {A(it+1), B(it)}
  // (prologue: newest 8 = {A(1), B(0)}), so vmcnt(8) ==> A(it) landed.
  int buf = 0;                           // A(it) lives in lA[it % 3]
  for (int ih = 0; ih < 17; ++ih) {
    {                                    // even it = 2ih: compute pa, prefetch B->pb
      const int it = 2 * ih;
      asm volatile("s_waitcnt vmcnt(8)" ::: "memory");
      __builtin_amdgcn_s_barrier();      // everyone's A(it) in lA[buf]
      asm volatile("" ::: "memory");
      int bnext = buf + 2; if (bnext >= 3) bnext -= 3;
      stageA(it + 2, bnext);             // safe: lA[bnext]'s readers pre-barrier
      LOADB(it + 1, pb0, pb1, pb2, pb3);
      COMPUTE(buf, pa0, pa1, pa2, pa3);
      buf = (buf == 2) ? 0 : buf + 1;
    }
    {                                    // odd it = 2ih+1: compute pb, prefetch B->pa
      const int it = 2 * ih + 1;
      asm volatile("s_waitcnt vmcnt(8)" ::: "memory");
      __builtin_amdgcn_s_barrier();
      asm volatile("" ::: "memory");
      if (it < 33) {                     // it=33 would stage A(35): handled here too
        int bnext = buf + 2; if (bnext >= 3) bnext -= 3;
        stageA(it + 2, bnext);
      } else {                           // it == 33: stage A(35) (last one)
        int bnext = buf + 2; if (bnext >= 3) bnext -= 3;
        stageA(35, bnext);
      }
      LOADB(it + 1, pa0, pa1, pa2, pa3);
      COMPUTE(buf, pb0, pb1, pb2, pb3);
      buf = (buf == 2) ? 0 : buf + 1;
    }
  }
  // it = 34 (pa): no A left to stage; prefetch B(35)->pb.
  // wait: newest 8 = {A(35), B(34)} -> vmcnt(8) ==> A(34) landed.
  asm volatile("s_waitcnt vmcnt(8)" ::: "memory");
  __builtin_amdgcn_s_barrier();
  asm volatile("" ::: "memory");
  LOADB(35, pb0, pb1, pb2, pb3);
  COMPUTE(buf, pa0, pa1, pa2, pa3);
  buf = (buf == 2) ? 0 : buf + 1;
  // it = 35 (pb): wait: outstanding <= {A(35), B(34), B(35)} = 12; vmcnt(8)
  // retires A(35) (oldest). B(35) readiness = compiler reg-dep wait.
  asm volatile("s_waitcnt vmcnt(8)" ::: "memory");
  __builtin_amdgcn_s_barrier();
  asm volatile("" ::: "memory");
  COMPUTE(buf, pb0, pb1, pb2, pb3);

  // epilogue: row(M) = wm*64 + r*16 + quad*4 + reg, col(N) = n0 + wn*32 + c*16 + l15
  float* obase = out + (size_t)bidx * (COUT * 1024);
  #define STORE(r, c, A) do {                                                   \
    const int _co = n0 + wn * 32 + (c) * 16 + l15;                              \
    const int _q  = q0 + wm * 64 + (r) * 16 + quad * 4;                         \
    f32x4 _v = A; _v += bias[_co];                                              \
    *(f32x4*)(obase + (size_t)_co * 1024 + _q) = _v;                            \
  } while (0)
  STORE(0, 0, acc00); STORE(0, 1, acc01);
  STORE(1, 0, acc10); STORE(1, 1, acc11);
  STORE(2, 0, acc20); STORE(2, 1, acc21);
  STORE(3, 0, acc30); STORE(3, 1, acc31);
  #undef STORE
  #undef COMPUTE
  #undef LOADB
  #undef MFMA
}

extern "C" void kernel_launch(void* const* d_in, const int* in_sizes, int n_in,
                              void* d_out, int out_size, void* d_ws, size_t ws_size,
                              hipStream_t stream) {
  const float* x    = (const float*)d_in[0];
  const float* w    = (const float*)d_in[1];
  const float* bias = (const float*)d_in[2];
  float* out = (float*)d_out;
  uint16_t* xpad = (uint16_t*)d_ws;
  uint16_t* bwq  = xpad + XPAD_ELEMS;          // 256*2304 bf16

  prep_kernel<<<dim3(3376), dim3(256), 0, stream>>>(x, w, xpad, bwq);
  gemm_kernel<<<dim3(512), dim3(256), 0, stream>>>(xpad, bwq, bias, out);
}

// Round 10
// 132.178 us; speedup vs baseline: 1.1636x; 1.1636x over previous
//
#include <hip/hip_runtime.h>
#include <cstdint>

typedef __attribute__((ext_vector_type(8))) __bf16 bf16x8;
typedef __attribute__((ext_vector_type(4))) float f32x4;
typedef __attribute__((ext_vector_type(4))) uint32_t u32x4;

// ---- problem constants ----
#define NB   16
#define CIN  256
#define COUT 256
#define HP   66          // padded H
#define WP   66          // padded W
#define KTOT 2304        // 9*256
#define XPB  (HP*WP*256)            // elems per batch image = 1,115,136
#define XPAD_ELEMS (NB*XPB)

__device__ __forceinline__ uint16_t f2bf(float f) {
  uint32_t u = __builtin_bit_cast(uint32_t, f);
  u = (u + 0x7FFFu + ((u >> 16) & 1u)) >> 16;   // round-to-nearest-even
  return (uint16_t)u;
}

// ---------------- fused prep: xpose (2048 blk) | border (1040 blk) | wprep (288 blk)
__global__ void prep_kernel(const float* __restrict__ x, const float* __restrict__ w,
                            uint16_t* __restrict__ xpad, uint16_t* __restrict__ bw) {
  const int bid = blockIdx.x;
  const int tid = threadIdx.x;
  if (bid < 2048) {
    // transpose+cast: x NCHW fp32 -> xpad[b][h+1][w+1][c] bf16 (interior only)
    const int lane = tid & 63;
    const int wvi = tid >> 6;                 // 0..3
    const int chalf = bid & 1;
    const int h = (bid >> 1) & 63;
    const int b = bid >> 7;
    const int cg = lane >> 4;                 // 0..3
    const int w4 = (lane & 15) * 4;           // 0,4,...,60
    const int c0 = chalf * 128 + wvi * 32 + cg * 8;   // 8-channel group
    const float* src = x + ((size_t)(b * 256 + c0) * 64 + h) * 64 + w4;
    f32x4 v[8];
    #pragma unroll
    for (int j = 0; j < 8; ++j)
      v[j] = *(const f32x4*)(src + (size_t)j * 4096);
    uint16_t* dst = xpad + ((size_t)(b * HP + h + 1) * WP + 1 + w4) * 256 + c0;
    #pragma unroll
    for (int p = 0; p < 4; ++p) {             // 4 pixels per thread
      u32x4 d;
      #pragma unroll
      for (int k = 0; k < 4; ++k)
        d[k] = (uint32_t)f2bf(v[2 * k][p]) | ((uint32_t)f2bf(v[2 * k + 1][p]) << 16);
      *(u32x4*)(dst + p * 256) = d;
    }
  } else if (bid < 3088) {
    // zero the pad border (u64 stores)
    const int idx = (bid - 2048) * 256 + tid;   // 0 .. 266239 exact
    const int b = idx / 16640;
    const int r = idx - b * 16640;
    uint64_t* base = (uint64_t*)(xpad + (size_t)b * XPB);
    int off;
    if (r < 4224) {                    // h=0 full row
      off = r;
    } else if (r < 8448) {             // h=65 full row
      off = 274560 + (r - 4224);
    } else if (r < 12544) {            // w=0 column, h=1..64
      const int i = r - 8448;
      off = (1 + (i >> 6)) * 4224 + (i & 63);
    } else {                           // w=65 column, h=1..64
      const int i = r - 12544;
      off = (1 + (i >> 6)) * 4224 + 4160 + (i & 63);
    }
    base[off] = 0;
  } else {
    // weight reorder: w[co][ci][3][3] fp32 -> bw[co][tap][ci] bf16
    const int gid = (bid - 3088) * 256 + tid;   // 0 .. 73727
    const int co = gid / 288;                   // 288 = 9 taps * 32 ci-groups
    const int r = gid - co * 288;
    const int tap = r >> 5;
    const int ci0 = (r & 31) * 8;
    u32x4 d;
    #pragma unroll
    for (int k = 0; k < 4; ++k) {
      const float v0 = w[((co * 256 + ci0 + 2 * k + 0) * 9) + tap];
      const float v1 = w[((co * 256 + ci0 + 2 * k + 1) * 9) + tap];
      d[k] = (uint32_t)f2bf(v0) | ((uint32_t)f2bf(v1) << 16);
    }
    *(u32x4*)(bw + co * KTOT + tap * 256 + ci0) = d;
  }
}

// ---------------- async 16B global -> LDS --------------------------------------------
__device__ __forceinline__ void gl_lds16(const void* g, void* l) {
  __builtin_amdgcn_global_load_lds(
      (__attribute__((address_space(1))) void*)(uintptr_t)g,
      (__attribute__((address_space(3))) void*)(uint32_t)(uintptr_t)l,
      16, 0, 0);
}

// ---------------- implicit GEMM v11 = v9 (129.4 us verified) + s_setprio on MFMA ----
// BM=128, BN=64, BK=64; 256 threads (4 waves, 2x2 grid, wave tile 64x32).
// 3-buffer LDS (A 16 KB + B 8 KB per buf = 72 KB), depth-2 prefetch, counted
// s_waitcnt vmcnt(6) + raw s_barrier (loads span barriers; all loop VMEM is
// global_load_lds -> manual count exact; NO register-consumed loads in the loop,
// the round-9 lesson). 512 blocks -> 2 independent pipelines/CU.
// v9 is ~87% of its LDS wall (144 KB/CU-iter ~ 1286 cyc vs ~1467 measured);
// setprio(1) around the MFMA cluster biases SIMD issue toward MFMA-phase waves
// vs the co-resident block's staging waves (T5: pays in phase-diverse regimes).
__global__ __launch_bounds__(256, 2) void gemm_kernel(
    const uint16_t* __restrict__ xpad, const uint16_t* __restrict__ bw,
    const float* __restrict__ bias, float* __restrict__ out) {
  __shared__ uint16_t lA[3][128 * 64];   // 16 KB per buffer
  __shared__ uint16_t lB[3][64 * 64];    //  8 KB per buffer -> 72 KB total
  const int tid = threadIdx.x;
  const int wv = tid >> 6, lane = tid & 63;
  const int quad = lane >> 4, l15 = lane & 15, l7 = lane & 7;
  const int wm = wv >> 1, wn = wv & 1;     // 2x2 wave grid: wave tile 64(M) x 32(N)

  // XCD swizzle: 4 n-tiles of one m-tile consecutive on one XCD (A L2-local)
  const int xcd = blockIdx.x & 7;
  const int grp = blockIdx.x >> 3;        // 0..63 per XCD
  const int mtile = xcd * 16 + (grp >> 2);   // 0..127
  const int ntile = grp & 3;                 // 0..3
  const int n0 = ntile * 64;
  const int m0 = mtile * 128;
  const int bidx = m0 >> 10;              // batch image
  const int q0 = m0 & 1023;               // permuted pixel offset (multiple of 128)

  // A staging: 4 chunk-slots/thread (1024 chunks of 16B); XOR chunk swizzle
  int a_goff[4];
  #pragma unroll
  for (int t = 0; t < 4; ++t) {
    const int slot = t * 256 + tid;
    const int row = slot >> 3;            // 0..127
    const int kc = (slot & 7) ^ (row & 7);
    const int p = q0 + row;
    const int oh = 2 * ((p >> 4) & 15) + ((p >> 9) & 1);
    const int ow = 2 * (p & 15) + ((p >> 8) & 1);
    a_goff[t] = ((bidx * HP + 2 * oh) * WP + 2 * ow) * 256 + kc * 8;
  }
  // B staging: 2 chunk-slots/thread (512 chunks)
  int b_goff[2];
  #pragma unroll
  for (int t = 0; t < 2; ++t) {
    const int slot = t * 256 + tid;
    const int n = slot >> 3;              // 0..63
    const int kc = (slot & 7) ^ (n & 7);
    b_goff[t] = (n0 + n) * KTOT + kc * 8;
  }

  // LDS frag byte-offsets (swizzle-matched)
  int aoff[4][2], boff[2][2];
  #pragma unroll
  for (int r = 0; r < 4; ++r)
    #pragma unroll
    for (int s = 0; s < 2; ++s)
      aoff[r][s] = (wm * 64 + r * 16 + l15) * 128 + (((s * 4 + quad) ^ l7) * 16);
  #pragma unroll
  for (int c = 0; c < 2; ++c)
    #pragma unroll
    for (int s = 0; s < 2; ++s)
      boff[c][s] = (wn * 32 + c * 16 + l15) * 128 + (((s * 4 + quad) ^ l7) * 16);

  f32x4 acc[4][2];
  #pragma unroll
  for (int r = 0; r < 4; ++r)
    #pragma unroll
    for (int c = 0; c < 2; ++c)
      acc[r][c] = (f32x4){0.f, 0.f, 0.f, 0.f};

  auto stage = [&](int it, int buf) {
    const int tap = it >> 2;
    const int kh = tap / 3, kw = tap - kh * 3;
    const int ci0 = (it & 3) << 6;
    const uint16_t* aptr = xpad + (kh * WP + kw) * 256 + ci0;
    const uint16_t* bptr = bw + tap * 256 + ci0;
    char* la_ = (char*)&lA[buf][0];
    char* lb_ = (char*)&lB[buf][0];
    #pragma unroll
    for (int t = 0; t < 4; ++t)
      gl_lds16(aptr + a_goff[t], la_ + (t * 256 + wv * 64) * 16);
    #pragma unroll
    for (int t = 0; t < 2; ++t)
      gl_lds16(bptr + b_goff[t], lb_ + (t * 256 + wv * 64) * 16);
  };

  auto compute = [&](int buf) {
    const char* la = (const char*)&lA[buf][0];
    const char* lb = (const char*)&lB[buf][0];
    #pragma unroll
    for (int s = 0; s < 2; ++s) {
      bf16x8 af[4], bfr[2];
      #pragma unroll
      for (int r = 0; r < 4; ++r) af[r] = *(const bf16x8*)(la + aoff[r][s]);
      #pragma unroll
      for (int c = 0; c < 2; ++c) bfr[c] = *(const bf16x8*)(lb + boff[c][s]);
      __builtin_amdgcn_s_setprio(1);
      #pragma unroll
      for (int r = 0; r < 4; ++r)
        #pragma unroll
        for (int c = 0; c < 2; ++c)
          acc[r][c] = __builtin_amdgcn_mfma_f32_16x16x32_bf16(af[r], bfr[c], acc[r][c], 0, 0, 0);
      __builtin_amdgcn_s_setprio(0);
    }
  };

  // prologue: 2-deep prefetch
  stage(0, 0);
  stage(1, 1);
  int buf = 0;
  for (int it = 0; it < 35; ++it) {
    // my stage(it)'s 6 chunks landed (stage(it+1)'s 6 may remain in flight)
    asm volatile("s_waitcnt vmcnt(6)" ::: "memory");
    __builtin_amdgcn_s_barrier();        // everyone's stage(it) landed
    asm volatile("" ::: "memory");       // keep ds_reads below the barrier
    if (it < 34) {
      int bnext = buf + 2; if (bnext >= 3) bnext -= 3;
      stage(it + 2, bnext);              // safe: last readers of bnext pre-barrier
    }
    compute(buf);
    buf = (buf == 2) ? 0 : buf + 1;
  }
  // peeled last iteration: nothing newer in flight -> full wait
  asm volatile("s_waitcnt vmcnt(0)" ::: "memory");
  __builtin_amdgcn_s_barrier();
  asm volatile("" ::: "memory");
  compute(buf);

  // epilogue: row(M) = wm*64 + r*16 + quad*4 + reg, col(N) = n0 + wn*32 + c*16 + l15
  float* obase = out + (size_t)bidx * (COUT * 1024);
  #pragma unroll
  for (int c = 0; c < 2; ++c) {
    const int co = n0 + wn * 32 + c * 16 + l15;
    const float bv = bias[co];
    #pragma unroll
    for (int r = 0; r < 4; ++r) {
      const int q = q0 + wm * 64 + r * 16 + quad * 4;
      f32x4 v = acc[r][c];
      v += bv;
      *(f32x4*)(obase + (size_t)co * 1024 + q) = v;
    }
  }
}

extern "C" void kernel_launch(void* const* d_in, const int* in_sizes, int n_in,
                              void* d_out, int out_size, void* d_ws, size_t ws_size,
                              hipStream_t stream) {
  const float* x    = (const float*)d_in[0];
  const float* w    = (const float*)d_in[1];
  const float* bias = (const float*)d_in[2];
  float* out = (float*)d_out;
  uint16_t* xpad = (uint16_t*)d_ws;
  uint16_t* bwq  = xpad + XPAD_ELEMS;          // 256*2304 bf16

  prep_kernel<<<dim3(3376), dim3(256), 0, stream>>>(x, w, xpad, bwq);
  gemm_kernel<<<dim3(512), dim3(256), 0, stream>>>(xpad, bwq, bias, out);
}

// Round 11
// 130.792 us; speedup vs baseline: 1.1759x; 1.0106x over previous
//
#include <hip/hip_runtime.h>
#include <cstdint>

typedef __attribute__((ext_vector_type(8))) __bf16 bf16x8;
typedef __attribute__((ext_vector_type(4))) float f32x4;
typedef __attribute__((ext_vector_type(4))) uint32_t u32x4;

// ---- problem constants ----
#define NB   16
#define CIN  256
#define COUT 256
#define HP   66          // padded H
#define WP   66          // padded W
#define KTOT 2304        // 9*256
#define XPB  (HP*WP*256)            // elems per batch image = 1,115,136
#define XPAD_ELEMS (NB*XPB)

__device__ __forceinline__ uint16_t f2bf(float f) {
  uint32_t u = __builtin_bit_cast(uint32_t, f);
  u = (u + 0x7FFFu + ((u >> 16) & 1u)) >> 16;   // round-to-nearest-even
  return (uint16_t)u;
}

// ---------------- fused prep: xpose (2048 blk) | border (1040 blk) | wprep (288 blk)
__global__ void prep_kernel(const float* __restrict__ x, const float* __restrict__ w,
                            uint16_t* __restrict__ xpad, uint16_t* __restrict__ bw) {
  const int bid = blockIdx.x;
  const int tid = threadIdx.x;
  if (bid < 2048) {
    // transpose+cast: x NCHW fp32 -> xpad[b][h+1][w+1][c] bf16 (interior only)
    const int lane = tid & 63;
    const int wvi = tid >> 6;                 // 0..3
    const int chalf = bid & 1;
    const int h = (bid >> 1) & 63;
    const int b = bid >> 7;
    const int cg = lane >> 4;                 // 0..3
    const int w4 = (lane & 15) * 4;           // 0,4,...,60
    const int c0 = chalf * 128 + wvi * 32 + cg * 8;   // 8-channel group
    const float* src = x + ((size_t)(b * 256 + c0) * 64 + h) * 64 + w4;
    f32x4 v[8];
    #pragma unroll
    for (int j = 0; j < 8; ++j)
      v[j] = *(const f32x4*)(src + (size_t)j * 4096);
    uint16_t* dst = xpad + ((size_t)(b * HP + h + 1) * WP + 1 + w4) * 256 + c0;
    #pragma unroll
    for (int p = 0; p < 4; ++p) {             // 4 pixels per thread
      u32x4 d;
      #pragma unroll
      for (int k = 0; k < 4; ++k)
        d[k] = (uint32_t)f2bf(v[2 * k][p]) | ((uint32_t)f2bf(v[2 * k + 1][p]) << 16);
      *(u32x4*)(dst + p * 256) = d;
    }
  } else if (bid < 3088) {
    // zero the pad border (u64 stores)
    const int idx = (bid - 2048) * 256 + tid;   // 0 .. 266239 exact
    const int b = idx / 16640;
    const int r = idx - b * 16640;
    uint64_t* base = (uint64_t*)(xpad + (size_t)b * XPB);
    int off;
    if (r < 4224) {                    // h=0 full row
      off = r;
    } else if (r < 8448) {             // h=65 full row
      off = 274560 + (r - 4224);
    } else if (r < 12544) {            // w=0 column, h=1..64
      const int i = r - 8448;
      off = (1 + (i >> 6)) * 4224 + (i & 63);
    } else {                           // w=65 column, h=1..64
      const int i = r - 12544;
      off = (1 + (i >> 6)) * 4224 + 4160 + (i & 63);
    }
    base[off] = 0;
  } else {
    // weight reorder: w[co][ci][3][3] fp32 -> bw[co][tap][ci] bf16
    const int gid = (bid - 3088) * 256 + tid;   // 0 .. 73727
    const int co = gid / 288;                   // 288 = 9 taps * 32 ci-groups
    const int r = gid - co * 288;
    const int tap = r >> 5;
    const int ci0 = (r & 31) * 8;
    u32x4 d;
    #pragma unroll
    for (int k = 0; k < 4; ++k) {
      const float v0 = w[((co * 256 + ci0 + 2 * k + 0) * 9) + tap];
      const float v1 = w[((co * 256 + ci0 + 2 * k + 1) * 9) + tap];
      d[k] = (uint32_t)f2bf(v0) | ((uint32_t)f2bf(v1) << 16);
    }
    *(u32x4*)(bw + co * KTOT + tap * 256 + ci0) = d;
  }
}

// ---------------- async 16B global -> LDS --------------------------------------------
__device__ __forceinline__ void gl_lds16(const void* g, void* l) {
  __builtin_amdgcn_global_load_lds(
      (__attribute__((address_space(1))) void*)(uintptr_t)g,
      (__attribute__((address_space(3))) void*)(uint32_t)(uintptr_t)l,
      16, 0, 0);
}

// ---------------- implicit GEMM v9 (exact round-8 revert, verified 129.4 us) --------
// BM=128, BN=64, BK=64; 256 threads (4 waves, 2x2 grid, wave tile 64x32).
// 3-buffer LDS (A 16 KB + B 8 KB per buf = 72 KB), depth-2 prefetch, counted
// s_waitcnt vmcnt(6) + raw s_barrier: loads stay in flight across barriers; all
// loop VMEM is global_load_lds so the manual count is exact. 512 blocks ->
// 2 independent pipelines/CU (8 waves/CU). ~92% of the 19.3 us LDS-pipe wall.
// Session-refuted alternatives: 1-block/CU (serializes, 31-66 us), B-in-VGPR
// (breaks counted vmcnt -> compiler drains, 52 us), full-drain barriers (50 us),
// setprio on MFMA (neutral-to-negative, lockstep regime).
__global__ __launch_bounds__(256, 2) void gemm_kernel(
    const uint16_t* __restrict__ xpad, const uint16_t* __restrict__ bw,
    const float* __restrict__ bias, float* __restrict__ out) {
  __shared__ uint16_t lA[3][128 * 64];   // 16 KB per buffer
  __shared__ uint16_t lB[3][64 * 64];    //  8 KB per buffer -> 72 KB total
  const int tid = threadIdx.x;
  const int wv = tid >> 6, lane = tid & 63;
  const int quad = lane >> 4, l15 = lane & 15, l7 = lane & 7;
  const int wm = wv >> 1, wn = wv & 1;     // 2x2 wave grid: wave tile 64(M) x 32(N)

  // XCD swizzle: 4 n-tiles of one m-tile consecutive on one XCD (A L2-local)
  const int xcd = blockIdx.x & 7;
  const int grp = blockIdx.x >> 3;        // 0..63 per XCD
  const int mtile = xcd * 16 + (grp >> 2);   // 0..127
  const int ntile = grp & 3;                 // 0..3
  const int n0 = ntile * 64;
  const int m0 = mtile * 128;
  const int bidx = m0 >> 10;              // batch image
  const int q0 = m0 & 1023;               // permuted pixel offset (multiple of 128)

  // A staging: 4 chunk-slots/thread (1024 chunks of 16B); XOR chunk swizzle
  int a_goff[4];
  #pragma unroll
  for (int t = 0; t < 4; ++t) {
    const int slot = t * 256 + tid;
    const int row = slot >> 3;            // 0..127
    const int kc = (slot & 7) ^ (row & 7);
    const int p = q0 + row;
    const int oh = 2 * ((p >> 4) & 15) + ((p >> 9) & 1);
    const int ow = 2 * (p & 15) + ((p >> 8) & 1);
    a_goff[t] = ((bidx * HP + 2 * oh) * WP + 2 * ow) * 256 + kc * 8;
  }
  // B staging: 2 chunk-slots/thread (512 chunks)
  int b_goff[2];
  #pragma unroll
  for (int t = 0; t < 2; ++t) {
    const int slot = t * 256 + tid;
    const int n = slot >> 3;              // 0..63
    const int kc = (slot & 7) ^ (n & 7);
    b_goff[t] = (n0 + n) * KTOT + kc * 8;
  }

  // LDS frag byte-offsets (swizzle-matched)
  int aoff[4][2], boff[2][2];
  #pragma unroll
  for (int r = 0; r < 4; ++r)
    #pragma unroll
    for (int s = 0; s < 2; ++s)
      aoff[r][s] = (wm * 64 + r * 16 + l15) * 128 + (((s * 4 + quad) ^ l7) * 16);
  #pragma unroll
  for (int c = 0; c < 2; ++c)
    #pragma unroll
    for (int s = 0; s < 2; ++s)
      boff[c][s] = (wn * 32 + c * 16 + l15) * 128 + (((s * 4 + quad) ^ l7) * 16);

  f32x4 acc[4][2];
  #pragma unroll
  for (int r = 0; r < 4; ++r)
    #pragma unroll
    for (int c = 0; c < 2; ++c)
      acc[r][c] = (f32x4){0.f, 0.f, 0.f, 0.f};

  auto stage = [&](int it, int buf) {
    const int tap = it >> 2;
    const int kh = tap / 3, kw = tap - kh * 3;
    const int ci0 = (it & 3) << 6;
    const uint16_t* aptr = xpad + (kh * WP + kw) * 256 + ci0;
    const uint16_t* bptr = bw + tap * 256 + ci0;
    char* la_ = (char*)&lA[buf][0];
    char* lb_ = (char*)&lB[buf][0];
    #pragma unroll
    for (int t = 0; t < 4; ++t)
      gl_lds16(aptr + a_goff[t], la_ + (t * 256 + wv * 64) * 16);
    #pragma unroll
    for (int t = 0; t < 2; ++t)
      gl_lds16(bptr + b_goff[t], lb_ + (t * 256 + wv * 64) * 16);
  };

  auto compute = [&](int buf) {
    const char* la = (const char*)&lA[buf][0];
    const char* lb = (const char*)&lB[buf][0];
    #pragma unroll
    for (int s = 0; s < 2; ++s) {
      bf16x8 af[4], bfr[2];
      #pragma unroll
      for (int r = 0; r < 4; ++r) af[r] = *(const bf16x8*)(la + aoff[r][s]);
      #pragma unroll
      for (int c = 0; c < 2; ++c) bfr[c] = *(const bf16x8*)(lb + boff[c][s]);
      #pragma unroll
      for (int r = 0; r < 4; ++r)
        #pragma unroll
        for (int c = 0; c < 2; ++c)
          acc[r][c] = __builtin_amdgcn_mfma_f32_16x16x32_bf16(af[r], bfr[c], acc[r][c], 0, 0, 0);
    }
  };

  // prologue: 2-deep prefetch
  stage(0, 0);
  stage(1, 1);
  int buf = 0;
  for (int it = 0; it < 35; ++it) {
    // my stage(it)'s 6 chunks landed (stage(it+1)'s 6 may remain in flight)
    asm volatile("s_waitcnt vmcnt(6)" ::: "memory");
    __builtin_amdgcn_s_barrier();        // everyone's stage(it) landed
    asm volatile("" ::: "memory");       // keep ds_reads below the barrier
    if (it < 34) {
      int bnext = buf + 2; if (bnext >= 3) bnext -= 3;
      stage(it + 2, bnext);              // safe: last readers of bnext pre-barrier
    }
    compute(buf);
    buf = (buf == 2) ? 0 : buf + 1;
  }
  // peeled last iteration: nothing newer in flight -> full wait
  asm volatile("s_waitcnt vmcnt(0)" ::: "memory");
  __builtin_amdgcn_s_barrier();
  asm volatile("" ::: "memory");
  compute(buf);

  // epilogue: row(M) = wm*64 + r*16 + quad*4 + reg, col(N) = n0 + wn*32 + c*16 + l15
  float* obase = out + (size_t)bidx * (COUT * 1024);
  #pragma unroll
  for (int c = 0; c < 2; ++c) {
    const int co = n0 + wn * 32 + c * 16 + l15;
    const float bv = bias[co];
    #pragma unroll
    for (int r = 0; r < 4; ++r) {
      const int q = q0 + wm * 64 + r * 16 + quad * 4;
      f32x4 v = acc[r][c];
      v += bv;
      *(f32x4*)(obase + (size_t)co * 1024 + q) = v;
    }
  }
}

extern "C" void kernel_launch(void* const* d_in, const int* in_sizes, int n_in,
                              void* d_out, int out_size, void* d_ws, size_t ws_size,
                              hipStream_t stream) {
  const float* x    = (const float*)d_in[0];
  const float* w    = (const float*)d_in[1];
  const float* bias = (const float*)d_in[2];
  float* out = (float*)d_out;
  uint16_t* xpad = (uint16_t*)d_ws;
  uint16_t* bwq  = xpad + XPAD_ELEMS;          // 256*2304 bf16

  prep_kernel<<<dim3(3376), dim3(256), 0, stream>>>(x, w, xpad, bwq);
  gemm_kernel<<<dim3(512), dim3(256), 0, stream>>>(xpad, bwq, bias, out);
}